// Round 1
// baseline (333.313 us; speedup 1.0000x reference)
//
#include <hip/hip_runtime.h>

#define N_NODES 100000
#define HID 64
#define N_EDGES 1600000
#define NB 391                 // ceil(N_NODES / 256) buckets of 256 nodes
#define C_EPB 6400             // edges per block in bucket_scatter (250 blocks)
#define GATHER_BLOCKS 6250     // N_NODES*16/256 gather blocks in fused prep kernel

typedef __attribute__((ext_vector_type(8))) short bf16x8;
typedef __attribute__((ext_vector_type(4))) float f32x4;

// ---- bf16 helpers (manual, RNE) ------------------------------------------
__device__ __forceinline__ unsigned short f2bf(float f) {
    unsigned u = __float_as_uint(f);
    u = (u + 0x7FFFu + ((u >> 16) & 1u)) >> 16;
    return (unsigned short)u;
}
__device__ __forceinline__ float bf2f(unsigned short h) {
    return __uint_as_float(((unsigned)h) << 16);
}
__device__ __forceinline__ float bflo(unsigned w) { return __uint_as_float(w << 16); }
__device__ __forceinline__ float bfhi(unsigned w) { return __uint_as_float(w & 0xFFFF0000u); }

// ------------------------------------------------- fused gather->bf16 + hist
// Blocks [0, GATHER_BLOCKS): xh = bf16(emb[node_id])   (independent of hist)
// Blocks [GATHER_BLOCKS, GATHER_BLOCKS+256): dst-bucket histogram for CSR sort
__global__ void gather_hist_kernel(const float* __restrict__ emb,
                                   const int* __restrict__ nid,
                                   unsigned short* __restrict__ xh,
                                   const int* __restrict__ dst,
                                   int* __restrict__ bhist) {
    if (blockIdx.x < GATHER_BLOCKS) {
        int i = blockIdx.x * blockDim.x + threadIdx.x;
        const int total = N_NODES * (HID / 4);
        if (i >= total) return;
        int row = i >> 4;
        int c   = i & 15;
        int s   = nid[row];
        float4 v = reinterpret_cast<const float4*>(emb)[(size_t)s * 16 + c];
        uint2 p;
        p.x = (unsigned)f2bf(v.x) | ((unsigned)f2bf(v.y) << 16);
        p.y = (unsigned)f2bf(v.z) | ((unsigned)f2bf(v.w) << 16);
        reinterpret_cast<uint2*>(xh)[(size_t)row * 16 + c] = p;
        return;
    }
    // ---- histogram part (256 blocks)
    __shared__ int h[NB];
    for (int i = threadIdx.x; i < NB; i += blockDim.x) h[i] = 0;
    __syncthreads();
    int hb = blockIdx.x - GATHER_BLOCKS;
    const int nt = 256 * 256;
    const int4* d4 = (const int4*)dst;
    for (int q = hb * blockDim.x + threadIdx.x; q < N_EDGES / 4; q += nt) {
        int4 v = d4[q];
        atomicAdd(&h[v.x >> 8], 1);
        atomicAdd(&h[v.y >> 8], 1);
        atomicAdd(&h[v.z >> 8], 1);
        atomicAdd(&h[v.w >> 8], 1);
    }
    __syncthreads();
    for (int i = threadIdx.x; i < NB; i += blockDim.x)
        if (h[i]) atomicAdd(&bhist[i], h[i]);
}

// ---------------------------------------------------------------- CSR build, pass B
__global__ void bucket_scan(const int* __restrict__ bhist,
                            int* __restrict__ boff,
                            int* __restrict__ bcursor) {
    __shared__ int s[512];
    int v = (threadIdx.x < NB) ? bhist[threadIdx.x] : 0;
    s[threadIdx.x] = v;
    __syncthreads();
    for (int off = 1; off < 512; off <<= 1) {
        int t = (threadIdx.x >= off) ? s[threadIdx.x - off] : 0;
        __syncthreads();
        s[threadIdx.x] += t;
        __syncthreads();
    }
    if (threadIdx.x < NB) {
        int ex = s[threadIdx.x] - v;
        boff[threadIdx.x] = ex;
        bcursor[threadIdx.x] = ex;
    }
}

// ---------------------------------------------------------------- CSR build, pass C
// pairs.y packs (eid << 8) | (dst & 255): bucket id is implied by slot range,
// so the freed high bits carry the original edge index through the sort.
__global__ void bucket_scatter(const int* __restrict__ src,
                               const int* __restrict__ dst,
                               int* __restrict__ bcursor,
                               int2* __restrict__ pairs) {
    __shared__ int h[NB];
    __shared__ int base[NB];
    for (int i = threadIdx.x; i < NB; i += blockDim.x) h[i] = 0;
    __syncthreads();
    int e0 = blockIdx.x * C_EPB;
    int e1 = e0 + C_EPB; if (e1 > N_EDGES) e1 = N_EDGES;
    for (int e = e0 + threadIdx.x; e < e1; e += blockDim.x)
        atomicAdd(&h[dst[e] >> 8], 1);
    __syncthreads();
    for (int i = threadIdx.x; i < NB; i += blockDim.x) {
        int c = h[i];
        base[i] = c ? atomicAdd(&bcursor[i], c) : 0;
    }
    __syncthreads();
    for (int i = threadIdx.x; i < NB; i += blockDim.x) h[i] = 0;
    __syncthreads();
    for (int e = e0 + threadIdx.x; e < e1; e += blockDim.x) {
        int d = dst[e];
        int b = d >> 8;
        int slot = base[b] + atomicAdd(&h[b], 1);
        pairs[slot] = make_int2(src[e], (d & 255) | (e << 8));
    }
}

// ---------------------------------------------------------------- CSR build, pass D
// Also unpacks the edge id into eord[] (same permutation as adj[]) so the
// classifier can run dst-grouped and scatter results back to edge order.
__global__ void bucket_csr(const int2* __restrict__ pairs,
                           const int* __restrict__ boff,
                           const int* __restrict__ bcursor,
                           int* __restrict__ row_start,
                           int* __restrict__ adj,
                           int* __restrict__ eord) {
    __shared__ int cnt[256];
    __shared__ int sc[256];
    int b = blockIdx.x;
    int node0 = b << 8;
    int p0 = boff[b];
    int p1 = bcursor[b];           // after pass C, bcursor[b] = end of bucket b
    int t = threadIdx.x;
    cnt[t] = 0;
    __syncthreads();
    for (int p = p0 + t; p < p1; p += 256)
        atomicAdd(&cnt[pairs[p].y & 255], 1);
    __syncthreads();
    int v = cnt[t];
    sc[t] = v;
    __syncthreads();
    for (int off = 1; off < 256; off <<= 1) {
        int u = (t >= off) ? sc[t - off] : 0;
        __syncthreads();
        sc[t] += u;
        __syncthreads();
    }
    sc[t] = p0 + sc[t] - v;        // exclusive scan + bucket base = row_start
    __syncthreads();
    int node = node0 + t;
    if (node <= N_NODES) row_start[node] = sc[t];
    __syncthreads();               // row_start read before atomics mutate sc
    for (int p = p0 + t; p < p1; p += 256) {
        int2 pr = pairs[p];
        int slot = atomicAdd(&sc[pr.y & 255], 1);
        adj[slot] = pr.x;
        eord[slot] = (int)(((unsigned)pr.y) >> 8);
    }
}

// ---------------------------------------------------------------- aggregation
// Pure gather+mean, NO LDS. 4 edge-slots x 16 lanes, uint2 loads.
// Grid 2048 (8 blocks/CU -> 32 waves/CU): agg is latency-bound at 1.2 TB/s
// fill (R8), well under the ~3.7 TB/s L2-miss path ceiling (R3/R5).
__global__ void agg_kernel(const int* __restrict__ row_start,
                           const int* __restrict__ adj,
                           const unsigned short* __restrict__ xh,
                           unsigned short* __restrict__ M) {
    int lane = threadIdx.x & 63;
    int slot = lane >> 4;               // 0..3  edge slot
    int c    = lane & 15;               // uint2 column (features 4c..4c+3)
    int wpb = blockDim.x >> 6;
    int wid = blockIdx.x * wpb + (threadIdx.x >> 6);
    int stride = gridDim.x * wpb;
    const uint2* xw = (const uint2*)xh;   // row stride = 16 uint2
    uint2* Mw = (uint2*)M;
    for (int row = wid; row < N_NODES; row += stride) {
        int beg = row_start[row], end = row_start[row + 1];
        float a0 = 0.f, a1 = 0.f, a2 = 0.f, a3 = 0.f;
        int j = beg + slot;
        for (; j + 12 < end; j += 16) {   // 4 uint2 gathers in flight per slot
            int s0 = adj[j], s1 = adj[j + 4], s2 = adj[j + 8], s3 = adj[j + 12];
            uint2 v0 = xw[(size_t)s0 * 16 + c];
            uint2 v1 = xw[(size_t)s1 * 16 + c];
            uint2 v2 = xw[(size_t)s2 * 16 + c];
            uint2 v3 = xw[(size_t)s3 * 16 + c];
            a0 += bflo(v0.x) + bflo(v1.x) + bflo(v2.x) + bflo(v3.x);
            a1 += bfhi(v0.x) + bfhi(v1.x) + bfhi(v2.x) + bfhi(v3.x);
            a2 += bflo(v0.y) + bflo(v1.y) + bflo(v2.y) + bflo(v3.y);
            a3 += bfhi(v0.y) + bfhi(v1.y) + bfhi(v2.y) + bfhi(v3.y);
        }
        for (; j < end; j += 4) {
            uint2 v = xw[(size_t)adj[j] * 16 + c];
            a0 += bflo(v.x); a1 += bfhi(v.x);
            a2 += bflo(v.y); a3 += bfhi(v.y);
        }
        a0 += __shfl_xor(a0, 16); a0 += __shfl_xor(a0, 32);
        a1 += __shfl_xor(a1, 16); a1 += __shfl_xor(a1, 32);
        a2 += __shfl_xor(a2, 16); a2 += __shfl_xor(a2, 32);
        a3 += __shfl_xor(a3, 16); a3 += __shfl_xor(a3, 32);
        if (slot == 0) {
            float inv = 1.0f / fmaxf((float)(end - beg), 1.0f);
            uint2 p;
            p.x = (unsigned)f2bf(a0 * inv) | ((unsigned)f2bf(a1 * inv) << 16);
            p.y = (unsigned)f2bf(a2 * inv) | ((unsigned)f2bf(a3 * inv) << 16);
            Mw[(size_t)row * 16 + c] = p;   // 16 lanes x 8B = 128B coalesced
        }
    }
}

// ---------------------------------------------------------------- MFMA GEMM
__global__ void gemm_kernel(const unsigned short* __restrict__ Am,
                            const unsigned short* __restrict__ As,
                            const float* __restrict__ Wl,
                            const float* __restrict__ Wr,
                            const float* __restrict__ bias,
                            unsigned short* __restrict__ H,
                            int relu) {
    int lane = threadIdx.x & 63;
    int m = lane & 15, quad = lane >> 4;

    bf16x8 wf[2][2][4];   // [matrix][kstep][ctile]
    for (int mat = 0; mat < 2; ++mat) {
        const float* W = mat ? Wr : Wl;
        for (int ks = 0; ks < 2; ++ks)
            for (int ct = 0; ct < 4; ++ct) {
                const float* p = W + (ct * 16 + m) * HID + ks * 32 + quad * 8;
                bf16x8 f;
                #pragma unroll
                for (int j = 0; j < 8; ++j) f[j] = (short)f2bf(p[j]);
                wf[mat][ks][ct] = f;
            }
    }
    float bv[4];
    #pragma unroll
    for (int ct = 0; ct < 4; ++ct) bv[ct] = bias[ct * 16 + m];

    int wpb = blockDim.x >> 6;
    int wid = blockIdx.x * wpb + (threadIdx.x >> 6);
    int stride = gridDim.x * wpb;
    const int NT = N_NODES / 16;
    for (int t = wid; t < NT; t += stride) {
        f32x4 acc[4] = {{0,0,0,0},{0,0,0,0},{0,0,0,0},{0,0,0,0}};
        size_t rowbase = ((size_t)t * 16 + m) * HID;
        #pragma unroll
        for (int ks = 0; ks < 2; ++ks) {
            bf16x8 a0 = *(const bf16x8*)(Am + rowbase + ks * 32 + quad * 8);
            bf16x8 a1 = *(const bf16x8*)(As + rowbase + ks * 32 + quad * 8);
            #pragma unroll
            for (int ct = 0; ct < 4; ++ct) {
                acc[ct] = __builtin_amdgcn_mfma_f32_16x16x32_bf16(a0, wf[0][ks][ct], acc[ct], 0, 0, 0);
                acc[ct] = __builtin_amdgcn_mfma_f32_16x16x32_bf16(a1, wf[1][ks][ct], acc[ct], 0, 0, 0);
            }
        }
        #pragma unroll
        for (int ct = 0; ct < 4; ++ct) {
            #pragma unroll
            for (int r = 0; r < 4; ++r) {
                float v = acc[ct][r] + bv[ct];
                if (relu) v = fmaxf(v, 0.f);
                H[((size_t)t * 16 + quad * 4 + r) * HID + ct * 16 + m] = f2bf(v);
            }
        }
    }
}

// ---------------------------------------------------------------- edge dot (CSR)
// Dst-grouped classifier: h[dst] is read ONCE per node (streaming, 12.8 MB)
// instead of randomly per edge (205 MB line traffic); only the src side stays
// a random gather. Results scatter to original edge order via eord[].
// Mirrors agg's tuned gather shape: 4 edge-slots x 16 lanes, uint2,
// 4 gathers in flight per slot.
__global__ void edge_dot_csr_kernel(const int* __restrict__ row_start,
                                    const int* __restrict__ adj,
                                    const int* __restrict__ eord,
                                    const unsigned short* __restrict__ h,
                                    float* __restrict__ out) {
    int lane = threadIdx.x & 63;
    int slot = lane >> 4;               // 0..3  edge slot
    int c    = lane & 15;               // uint2 column (features 4c..4c+3)
    int wpb = blockDim.x >> 6;
    int wid = blockIdx.x * wpb + (threadIdx.x >> 6);
    int stride = gridDim.x * wpb;
    const uint2* hw = (const uint2*)h;  // row stride = 16 uint2
    for (int row = wid; row < N_NODES; row += stride) {
        int beg = row_start[row], end = row_start[row + 1];
        if (beg == end) continue;
        uint2 vd = hw[(size_t)row * 16 + c];
        float d0 = bflo(vd.x), d1 = bfhi(vd.x), d2 = bflo(vd.y), d3 = bfhi(vd.y);
        int j = beg + slot;
        for (; j + 12 < end; j += 16) {   // 4 uint2 gathers in flight per slot
            int s0 = adj[j], s1 = adj[j + 4], s2 = adj[j + 8], s3 = adj[j + 12];
            int e0 = eord[j], e1 = eord[j + 4], e2 = eord[j + 8], e3 = eord[j + 12];
            uint2 v0 = hw[(size_t)s0 * 16 + c];
            uint2 v1 = hw[(size_t)s1 * 16 + c];
            uint2 v2 = hw[(size_t)s2 * 16 + c];
            uint2 v3 = hw[(size_t)s3 * 16 + c];
            float p0 = bflo(v0.x) * d0 + bfhi(v0.x) * d1 + bflo(v0.y) * d2 + bfhi(v0.y) * d3;
            float p1 = bflo(v1.x) * d0 + bfhi(v1.x) * d1 + bflo(v1.y) * d2 + bfhi(v1.y) * d3;
            float p2 = bflo(v2.x) * d0 + bfhi(v2.x) * d1 + bflo(v2.y) * d2 + bfhi(v2.y) * d3;
            float p3 = bflo(v3.x) * d0 + bfhi(v3.x) * d1 + bflo(v3.y) * d2 + bfhi(v3.y) * d3;
            p0 += __shfl_xor(p0, 1); p0 += __shfl_xor(p0, 2); p0 += __shfl_xor(p0, 4); p0 += __shfl_xor(p0, 8);
            p1 += __shfl_xor(p1, 1); p1 += __shfl_xor(p1, 2); p1 += __shfl_xor(p1, 4); p1 += __shfl_xor(p1, 8);
            p2 += __shfl_xor(p2, 1); p2 += __shfl_xor(p2, 2); p2 += __shfl_xor(p2, 4); p2 += __shfl_xor(p2, 8);
            p3 += __shfl_xor(p3, 1); p3 += __shfl_xor(p3, 2); p3 += __shfl_xor(p3, 4); p3 += __shfl_xor(p3, 8);
            if (c == 0) {
                out[e0] = p0; out[e1] = p1; out[e2] = p2; out[e3] = p3;
            }
        }
        for (; j < end; j += 4) {
            int s = adj[j];
            int e = eord[j];
            uint2 v = hw[(size_t)s * 16 + c];
            float p = bflo(v.x) * d0 + bfhi(v.x) * d1 + bflo(v.y) * d2 + bfhi(v.y) * d3;
            p += __shfl_xor(p, 1); p += __shfl_xor(p, 2); p += __shfl_xor(p, 4); p += __shfl_xor(p, 8);
            if (c == 0) out[e] = p;
        }
    }
}

extern "C" void kernel_launch(void* const* d_in, const int* in_sizes, int n_in,
                              void* d_out, int out_size, void* d_ws, size_t ws_size,
                              hipStream_t stream) {
    const float* emb = (const float*)d_in[0];
    const float* Wl1 = (const float*)d_in[1];
    const float* Wr1 = (const float*)d_in[2];
    const float* b1  = (const float*)d_in[3];
    const float* Wl2 = (const float*)d_in[4];
    const float* Wr2 = (const float*)d_in[5];
    const float* b2  = (const float*)d_in[6];
    const int*   nid = (const int*)d_in[7];
    const int*   ei  = (const int*)d_in[8];
    const int* esrc = ei;
    const int* edst = ei + N_EDGES;
    float* out = (float*)d_out;

    const size_t NH = (size_t)N_NODES * HID;   // 6.4M elements
    unsigned short* xh  = (unsigned short*)d_ws;          // [N,64] bf16
    unsigned short* h1h = xh + NH;                        // [N,64] bf16
    unsigned short* h2h = h1h + NH;                       // [N,64] bf16
    unsigned short* M   = h2h + NH;                       // [N,64] bf16 (mean agg)
    int* ib        = (int*)(M + NH);                      // int region
    int* row_start = ib;                          // [N+1]
    int* adj       = ib + N_NODES + 64;           // [E]  src per CSR slot
    int* eord      = adj + N_EDGES;               // [E]  original edge id per slot
    int2* pairs    = (int2*)(eord + N_EDGES);     // [E]  (src, (eid<<8)|(dst&255))
    int* bhist     = (int*)(pairs + N_EDGES);     // [NB]
    int* boff      = bhist + NB + 1;              // [NB]
    int* bcursor   = boff + NB + 1;               // [NB]

    hipMemsetAsync(bhist, 0, NB * sizeof(int), stream);

    // fused: xh = bf16(emb[node_id])  +  dst-bucket histogram
    gather_hist_kernel<<<GATHER_BLOCKS + 256, 256, 0, stream>>>(emb, nid, xh, edst, bhist);

    // ---- CSR build via bucket counting sort (shared by both layers)
    bucket_scan<<<1, 512, 0, stream>>>(bhist, boff, bcursor);
    bucket_scatter<<<(N_EDGES + C_EPB - 1) / C_EPB, 256, 0, stream>>>(esrc, edst, bcursor, pairs);
    bucket_csr<<<NB, 256, 0, stream>>>(pairs, boff, bcursor, row_start, adj, eord);

    // ---- layer 1: aggregate then MFMA GEMM (+relu)
    agg_kernel<<<2048, 256, 0, stream>>>(row_start, adj, xh, M);
    gemm_kernel<<<512, 256, 0, stream>>>(M, xh, Wl1, Wr1, b1, h1h, 1);

    // ---- layer 2
    agg_kernel<<<2048, 256, 0, stream>>>(row_start, adj, h1h, M);
    gemm_kernel<<<512, 256, 0, stream>>>(M, h1h, Wl2, Wr2, b2, h2h, 0);

    // ---- edge classifier, dst-grouped over CSR, scatter to edge order
    edge_dot_csr_kernel<<<2048, 256, 0, stream>>>(row_start, adj, eord, h2h, out);
}